// Round 20
// baseline (326.627 us; speedup 1.0000x reference)
//
#include <hip/hip_runtime.h>
#include <stdint.h>
#include <math.h>

typedef __attribute__((ext_vector_type(8))) short bf16x8;
typedef __attribute__((ext_vector_type(4))) float f32x4;
typedef __attribute__((ext_vector_type(4))) unsigned int u32x4;
typedef __attribute__((ext_vector_type(4))) unsigned short us16x4;

__device__ __forceinline__ unsigned short f2bf(float f){
  unsigned int u = __float_as_uint(f);
  u += 0x7fffu + ((u >> 16) & 1u);   // RNE
  return (unsigned short)(u >> 16);
}

__device__ __forceinline__ float bf2f(short s){
  return __uint_as_float(((unsigned int)(unsigned short)s) << 16);
}

// ssp(x) = softplus(x) - ln2 = max(x,0) + ln2*(log2(1 + 2^(-|x|*log2e)) - 1)
__device__ __forceinline__ float ssp_f(float x){
  float u = exp2f(-fabsf(x)*1.4426950408889634f);
  return fmaxf(x, 0.f) + 0.6931471805599453f*(__log2f(1.0f + u) - 1.0f);
}

// ---------------- count + fused weight prep ----------------
__global__ void k_count_prep(const int* __restrict__ eidx, int E, int* __restrict__ cnt,
                             const float* __restrict__ Wr0, const float* __restrict__ Wr1,
                             const float* __restrict__ Wsc_s, const float* __restrict__ Wsc_v,
                             const float* __restrict__ W1s, const float* __restrict__ W1v,
                             unsigned short* __restrict__ wr1frag, float* __restrict__ wr0p,
                             unsigned short* __restrict__ wscfrag, unsigned short* __restrict__ w1frag){
  int id = blockIdx.x*256 + threadIdx.x;
  if(id < 512) wr0p[id] = Wr0[(id & 7)*64 + (id >> 3)];
  if(id < 1024){
    int fi = id >> 6, lane = id & 63;
    int c0 = lane & 15, g = lane >> 4;
    int kt = fi >> 3, ct = fi & 7;
    unsigned short tmp[8];
    #pragma unroll
    for(int i = 0; i < 8; i++){
      int k = kt*32 + g*8 + i;
      tmp[i] = f2bf(Wr1[k*128 + ct*16 + c0]);
    }
    #pragma unroll
    for(int i = 0; i < 8; i++) wr1frag[id*8 + i] = tmp[i];
  }
  if(id < 4096){
    int sel  = id >> 11;
    int fi   = (id >> 6) & 31;
    int lane = id & 63;
    int c0 = lane & 15, g = lane >> 4;
    int ks = fi >> 1, ct = fi & 1;
    const float* W = sel ? Wsc_v : Wsc_s;
    bf16x8 tmp;
    #pragma unroll
    for(int i = 0; i < 8; i++){
      int k = ks*32 + g*8 + i;
      tmp[i] = (short)f2bf(W[k*32 + ct*16 + c0]);
    }
    *(bf16x8*)&wscfrag[(size_t)id*8] = tmp;
  }
  if(id < 256){
    int sel = id >> 7, ct = (id >> 6) & 1, lane = id & 63;
    int c0 = lane & 15, g = lane >> 4;
    const float* W = sel ? W1v : W1s;
    bf16x8 tmp;
    #pragma unroll
    for(int i = 0; i < 8; i++){
      int m = g*8 + i;
      tmp[i] = (short)f2bf(W[m*32 + ct*16 + c0]);
    }
    *(bf16x8*)&w1frag[(size_t)id*8] = tmp;
  }
  if(id < E) atomicAdd(&cnt[eidx[E + id]], 1);
}

// ---------------- CSR scan (parallel multi-block, round-5-validated) ----------------
__global__ void k_scan_a(const int* __restrict__ cnt, int N, int* __restrict__ offs, int* __restrict__ bsum){
  __shared__ int arr[1024];
  int t = threadIdx.x, i = blockIdx.x*1024 + t;
  int v = (i < N) ? cnt[i] : 0;
  int own = v;
  arr[t] = v;
  for(int off = 1; off < 1024; off <<= 1){
    __syncthreads();
    int u = (t >= off) ? arr[t - off] : 0;
    __syncthreads();
    arr[t] += u;
  }
  if(i < N) offs[i] = arr[t] - own;
  if(t == 1023) bsum[blockIdx.x] = arr[1023];
}

__global__ void k_scan_b(int* __restrict__ bsum, int NB, int* __restrict__ offs, int N){
  if(threadIdx.x == 0 && blockIdx.x == 0){
    int run = 0;
    for(int b = 0; b < NB; b++){ int t = bsum[b]; bsum[b] = run; run += t; }
    offs[N] = run;
  }
}

__global__ void k_scan_c(int* __restrict__ offs, const int* __restrict__ bsum, int* __restrict__ cursor, int N){
  int i = blockIdx.x*1024 + threadIdx.x;
  if(i < N){
    int v = offs[i] + bsum[blockIdx.x];
    offs[i] = v;
    cursor[i] = v;
  }
}

// permute edges into CSR order, packed 32B record per edge:
// bytes 0-15: eemb bf16x8; 16-23: eattr bf16x4; 24-27: src; 28-31 pad.
__global__ void k_perm(const float* __restrict__ eemb, const float* __restrict__ eattr,
                       const int* __restrict__ eidx, int E, int* __restrict__ cursor,
                       unsigned short* __restrict__ edata){
  int e = blockIdx.x*256 + threadIdx.x;
  if(e < E){
    int d = eidx[E + e];
    int dp = atomicAdd(&cursor[d], 1);
    f32x4 a = *(const f32x4*)(eemb + (size_t)e*8);
    f32x4 b = *(const f32x4*)(eemb + (size_t)e*8 + 4);
    bf16x8 pk;
    pk[0] = (short)f2bf(a[0]); pk[1] = (short)f2bf(a[1]);
    pk[2] = (short)f2bf(a[2]); pk[3] = (short)f2bf(a[3]);
    pk[4] = (short)f2bf(b[0]); pk[5] = (short)f2bf(b[1]);
    pk[6] = (short)f2bf(b[2]); pk[7] = (short)f2bf(b[3]);
    f32x4 ea = *(const f32x4*)(eattr + (size_t)e*4);
    unsigned int i0 = (unsigned int)f2bf(ea[0]) | ((unsigned int)f2bf(ea[1]) << 16);
    unsigned int i1 = (unsigned int)f2bf(ea[2]) | ((unsigned int)f2bf(ea[3]) << 16);
    u32x4 hi = { i0, i1, (unsigned int)eidx[e], 0u };
    *(bf16x8*)(edata + (size_t)dp*16) = pk;
    *(u32x4*)(edata + (size_t)dp*16 + 8) = hi;
  }
}

// ---------------- node kernel: sv via MFMA (bf16, swizzled layout) + self-connection ----------------
__global__ __launch_bounds__(256) void k_node(
    const float* __restrict__ nf, const float* __restrict__ na,
    const unsigned short* __restrict__ w1frag,
    const unsigned short* __restrict__ wscfrag,
    unsigned short* __restrict__ sv, float* __restrict__ out, int N)
{
  __shared__ float xl[64*133];
  __shared__ __align__(16) float al[64*20];
  const int t = threadIdx.x;
  const int n0 = blockIdx.x*64;

  for(int idx = t; idx < 64*128; idx += 256){
    int r = idx >> 7, c = idx & 127;
    int n = n0 + r;
    xl[r*133 + c] = (n < N) ? nf[(size_t)n*128 + c] : 0.f;
  }
  for(int idx = t; idx < 64*16; idx += 256){
    int r = idx >> 4, c = idx & 15;
    int n = n0 + r;
    al[r*20 + c] = (n < N) ? na[(size_t)n*16 + c] : 0.f;
  }
  __syncthreads();

  const float INVM = 0.17677669529663689f;   // 1/sqrt(32)
  const float FC   = 0.044194173824159216f;  // 1/sqrt(512)

  const int lane = t & 63, wv = t >> 6;
  const int c0 = lane & 15, g = lane >> 4;

  // ---- sv via MFMA ----
  {
    const unsigned short* w1f = w1frag + (size_t)((wv == 0) ? 0 : 1024);
    bf16x8 b0 = *(const bf16x8*)&w1f[(0*64 + lane)*8];
    bf16x8 b1 = *(const bf16x8*)&w1f[(1*64 + lane)*8];
    #pragma unroll
    for(int rt = 0; rt < 4; rt++){
      int row = rt*16 + c0;
      bf16x8 a;
      #pragma unroll
      for(int i = 0; i < 8; i++){
        int m = g*8 + i;
        float xv = (wv == 0) ? xl[row*133 + m] : xl[row*133 + 32 + 3*m + (wv-1)];
        a[i] = (short)f2bf(xv);
      }
      f32x4 z = {0.f,0.f,0.f,0.f};
      f32x4 d0 = __builtin_amdgcn_mfma_f32_16x16x32_bf16(a, b0, z, 0, 0, 0);
      f32x4 d1 = __builtin_amdgcn_mfma_f32_16x16x32_bf16(a, b1, z, 0, 0, 0);
      #pragma unroll
      for(int r = 0; r < 4; r++){
        int node = n0 + rt*16 + g*4 + r;
        if(node < N){
          sv[(size_t)node*128 + c0*8 + wv*2 + 0] = f2bf(d0[r]*INVM);
          sv[(size_t)node*128 + c0*8 + wv*2 + 1] = f2bf(d1[r]*INVM);
        }
      }
    }
  }

  // ---- self-connection MFMA ----
  const unsigned short* wf = wscfrag + (size_t)((wv == 0) ? 0 : 16384);

  f32x4 accm[4][2];
  #pragma unroll
  for(int rt = 0; rt < 4; rt++)
    #pragma unroll
    for(int ct = 0; ct < 2; ct++) accm[rt][ct] = (f32x4){0.f,0.f,0.f,0.f};

  for(int ks = 0; ks < 16; ks++){
    bf16x8 bfr[2];
    bfr[0] = *(const bf16x8*)&wf[(size_t)((ks*2 + 0)*64 + lane)*8];
    bfr[1] = *(const bf16x8*)&wf[(size_t)((ks*2 + 1)*64 + lane)*8];
    int u2 = ks*2 + (g >> 1);
    int ab = (g & 1)*8;
    #pragma unroll
    for(int rt = 0; rt < 4; rt++){
      int row = rt*16 + c0;
      float xv = (wv == 0) ? xl[row*133 + u2] : xl[row*133 + 32 + 3*u2 + (wv-1)];
      f32x4 v0 = *(const f32x4*)&al[row*20 + ab];
      f32x4 v1 = *(const f32x4*)&al[row*20 + ab + 4];
      bf16x8 a;
      a[0] = (short)f2bf(xv*v0[0]); a[1] = (short)f2bf(xv*v0[1]);
      a[2] = (short)f2bf(xv*v0[2]); a[3] = (short)f2bf(xv*v0[3]);
      a[4] = (short)f2bf(xv*v1[0]); a[5] = (short)f2bf(xv*v1[1]);
      a[6] = (short)f2bf(xv*v1[2]); a[7] = (short)f2bf(xv*v1[3]);
      #pragma unroll
      for(int ct = 0; ct < 2; ct++)
        accm[rt][ct] = __builtin_amdgcn_mfma_f32_16x16x32_bf16(a, bfr[ct], accm[rt][ct], 0, 0, 0);
    }
  }

  #pragma unroll
  for(int rt = 0; rt < 4; rt++)
    #pragma unroll
    for(int ct = 0; ct < 2; ct++)
      #pragma unroll
      for(int i = 0; i < 4; i++){
        int node = n0 + rt*16 + g*4 + i;
        if(node < N){
          int col = ct*16 + c0;
          float v = accm[rt][ct][i] * FC;
          if(wv == 0) out[(size_t)node*128 + col] = v;
          else        out[(size_t)node*128 + 32 + 3*col + (wv-1)] = v;
        }
      }
}

// ---------------- phase 1: w = (ssp(ee@Wr0)/sqrt8)@Wr1 * 1/8, CSR-ordered, bf16, col-swizzled ----
__global__ __launch_bounds__(256, 4) void k_wedge(
    const unsigned short* __restrict__ edata,
    const unsigned short* __restrict__ wr1frag, const float* __restrict__ wr0p,
    unsigned short* __restrict__ wper, int NB16, int E)
{
  __shared__ __align__(16) float wr0t[512];
  __shared__ __align__(16) unsigned short bwl[8192];
  const int t = threadIdx.x;
  {
    const f32x4* s4 = (const f32x4*)wr1frag;
    f32x4* d4 = (f32x4*)bwl;
    #pragma unroll
    for(int i = 0; i < 4; i++) d4[t + i*256] = s4[t + i*256];
    if(t < 128) ((f32x4*)wr0t)[t] = ((const f32x4*)wr0p)[t];
  }
  __syncthreads();

  const int lane = t & 63;
  const int wv   = t >> 6;
  const int c0   = lane & 15;
  const int g    = lane >> 4;
  const float S8 = 0.35355339059327373f;   // 1/sqrt(8)

  int p = blockIdx.x*4 + wv;
  if(p >= NB16) return;
  int p16 = p*16;
  int bc = E - p16; if(bc > 16) bc = 16;
  bool val = (c0 < bc);

  bf16x8 eb8 = *(const bf16x8*)(edata + (size_t)(p16 + (val ? c0 : 0))*16);
  float ee[8];
  #pragma unroll
  for(int i = 0; i < 8; i++) ee[i] = bf2f(eb8[i]);

  bf16x8 afr[2];
  #pragma unroll
  for(int kt = 0; kt < 2; kt++){
    bf16x8 a;
    #pragma unroll
    for(int i = 0; i < 8; i++){
      int j = kt*32 + g*8 + i;
      f32x4 wa = *(const f32x4*)&wr0t[j*8];
      f32x4 wb = *(const f32x4*)&wr0t[j*8 + 4];
      float pre = ee[0]*wa[0] + ee[1]*wa[1] + ee[2]*wa[2] + ee[3]*wa[3]
                + ee[4]*wb[0] + ee[5]*wb[1] + ee[6]*wb[2] + ee[7]*wb[3];
      a[i] = (short)f2bf(ssp_f(pre * S8));
    }
    afr[kt] = a;
  }

  f32x4 cfr[8];
  #pragma unroll
  for(int ct = 0; ct < 8; ct++) cfr[ct] = (f32x4){0.f,0.f,0.f,0.f};
  #pragma unroll
  for(int kt = 0; kt < 2; kt++)
    #pragma unroll
    for(int ct = 0; ct < 8; ct++){
      bf16x8 bfr = *(const bf16x8*)&bwl[((kt*8 + ct)*64 + lane)*8];
      cfr[ct] = __builtin_amdgcn_mfma_f32_16x16x32_bf16(afr[kt], bfr, cfr[ct], 0, 0, 0);
    }

  #pragma unroll
  for(int i = 0; i < 4; i++){
    if(g*4 + i < bc){
      bf16x8 wpk;
      #pragma unroll
      for(int ct = 0; ct < 8; ct++) wpk[ct] = (short)f2bf(cfr[ct][i] * 0.125f);
      *(bf16x8*)(wper + (size_t)(p16 + g*4 + i)*128 + c0*8) = wpk;
    }
  }
}

// ---------------- phase 2: node-centric gather + messages + bf16-W2 vectorized epilogue ----------------
// W2 staged TRANSPOSED in LDS as bf16, stride 68 shorts (136B rows, 8B-aligned):
// b64 reads hit bank (t1*34+2q)%32 -> all 32 banks x 2 lanes = conflict-free.
__global__ __launch_bounds__(256, 4) void k_msg(
    const unsigned short* __restrict__ sv, const unsigned short* __restrict__ wper,
    const unsigned short* __restrict__ edata, const int* __restrict__ offs,
    const float* __restrict__ W2s, const float* __restrict__ W2v,
    float* __restrict__ out, int N)
{
  __shared__ __align__(16) float nsl[4][256];         // [0..63]=ns, [64+c*64+m]=nv[c][m]
  __shared__ __align__(8) unsigned short w2sTb[32*68]; // w2sTb[o*68+m] = bf16(W2s[m][o])
  __shared__ __align__(8) unsigned short w2vTb[32*68]; // w2vTb[o*68+m] = bf16(W2v[m][o])
  const int t = threadIdx.x, lane = t & 63, wv = t >> 6;
  const int c0 = lane & 15, g = lane >> 4;

  {
    #pragma unroll
    for(int i = 0; i < 8; i++){
      int idx = t + i*256;          // 0..2047
      int m = idx >> 5, o = idx & 31;
      w2sTb[o*68 + m] = f2bf(W2s[idx]);
      w2vTb[o*68 + m] = f2bf(W2v[idx]);
    }
  }
  __syncthreads();

  const int n = blockIdx.x*4 + wv;
  if(n >= N) return;

  const float SC2 = 0.03125f;              // (1/sqrt64)*(1/sqrt16)
  const float IS3 = 0.57735026918962576f;  // 1/sqrt(3)

  float acc[16];
  #pragma unroll
  for(int i = 0; i < 16; i++) acc[i] = 0.f;

  const int eb0 = offs[n], eb1 = offs[n+1];
  for(int eb = eb0; eb < eb1; eb += 16){
    int bc = eb1 - eb; if(bc > 16) bc = 16;
    #pragma unroll
    for(int r = 0; r < 4; r++){
      int es = r*4 + g;
      if(es >= bc) continue;
      int e = eb + es;
      u32x4 rec = *(const u32x4*)(edata + (size_t)e*16 + 8);
      int s = (int)rec.z;
      bf16x8 sr = *(const bf16x8*)(sv + (size_t)s*128 + c0*8);
      bf16x8 w8 = *(const bf16x8*)(wper + (size_t)e*128 + c0*8);
      float e0  = bf2f((short)(rec.x & 0xffff));
      float e1x = bf2f((short)(rec.x >> 16));
      float e1y = bf2f((short)(rec.y & 0xffff));
      float e1z = bf2f((short)(rec.y >> 16));
      float w0A = bf2f(w8[0]), w0B = bf2f(w8[1]);
      float w1A = bf2f(w8[2]), w1B = bf2f(w8[3]);
      float w2A = bf2f(w8[4]), w2B = bf2f(w8[5]);
      float w3A = bf2f(w8[6]), w3B = bf2f(w8[7]);
      float ssA = bf2f(sr[0]), ssB = bf2f(sr[1]);
      float vA0 = bf2f(sr[2]), vB0 = bf2f(sr[3]);
      float vA1 = bf2f(sr[4]), vB1 = bf2f(sr[5]);
      float vA2 = bf2f(sr[6]), vB2 = bf2f(sr[7]);

      acc[0] += w0A*ssA*e0;
      acc[1] += w0B*ssB*e0;
      acc[2] += w3A*(vA0*e1x + vA1*e1y + vA2*e1z);
      acc[3] += w3B*(vB0*e1x + vB1*e1y + vB2*e1z);
      float h1A = w1A*ssA, h1B = w1B*ssB;
      acc[4]  += h1A*e1x; acc[5]  += h1A*e1y; acc[6]  += h1A*e1z;
      acc[7]  += h1B*e1x; acc[8]  += h1B*e1y; acc[9]  += h1B*e1z;
      float h2A = w2A*e0, h2B = w2B*e0;
      acc[10] += h2A*vA0; acc[11] += h2A*vA1; acc[12] += h2A*vA2;
      acc[13] += h2B*vB0; acc[14] += h2B*vB1; acc[15] += h2B*vB2;
    }
  }

  #pragma unroll
  for(int i = 0; i < 16; i++){
    acc[i] += __shfl_xor(acc[i], 16);
    acc[i] += __shfl_xor(acc[i], 32);
  }

  float* nl = nsl[wv];
  if(g == 0){
    nl[c0]      = acc[0];
    nl[16 + c0] = acc[1];
    nl[32 + c0] = acc[2]*IS3;
    nl[48 + c0] = acc[3]*IS3;
    #pragma unroll
    for(int cc = 0; cc < 3; cc++){
      nl[64 + cc*64 +  0 + c0] = acc[4  + cc];
      nl[64 + cc*64 + 16 + c0] = acc[7  + cc];
      nl[64 + cc*64 + 32 + c0] = acc[10 + cc];
      nl[64 + cc*64 + 48 + c0] = acc[13 + cc];
    }
  }
  __threadfence_block();

  const int t1 = lane, t2 = 64 + lane;
  int u1 = t1 - 32; if(u1 < 0) u1 = 0;
  const int w1i = u1/3, c1i = u1%3;
  const int w2i = (t2 - 32)/3, c2i = (t2 - 32)%3;
  const f32x4*  p1a = (const f32x4*)((t1 < 32) ? &nl[0] : &nl[64 + c1i*64]);
  const us16x4* p1b = (const us16x4*)((t1 < 32) ? &w2sTb[t1*68] : &w2vTb[w1i*68]);
  const f32x4*  p2a = (const f32x4*)&nl[64 + c2i*64];
  const us16x4* p2b = (const us16x4*)&w2vTb[w2i*68];
  float s1 = 0.f, s2 = 0.f;
  #pragma unroll
  for(int q = 0; q < 16; q++){
    f32x4 a = p1a[q];
    us16x4 b = p1b[q];
    f32x4 c = p2a[q];
    us16x4 d = p2b[q];
    s1 += a[0]*bf2f((short)b[0]) + a[1]*bf2f((short)b[1])
        + a[2]*bf2f((short)b[2]) + a[3]*bf2f((short)b[3]);
    s2 += c[0]*bf2f((short)d[0]) + c[1]*bf2f((short)d[1])
        + c[2]*bf2f((short)d[2]) + c[3]*bf2f((short)d[3]);
  }
  out[(size_t)n*128 + t1] += s1*SC2;
  out[(size_t)n*128 + t2] += s2*SC2;
}

extern "C" void kernel_launch(void* const* d_in, const int* in_sizes, int n_in,
                              void* d_out, int out_size, void* d_ws, size_t ws_size,
                              hipStream_t stream)
{
  const float* nf    = (const float*)d_in[0];
  const float* na    = (const float*)d_in[1];
  const float* eemb  = (const float*)d_in[2];
  const float* eattr = (const float*)d_in[3];
  const int*   eidx  = (const int*)d_in[4];
  const float* W1s   = (const float*)d_in[5];
  const float* W1v   = (const float*)d_in[6];
  const float* Wr0   = (const float*)d_in[7];
  const float* Wr1   = (const float*)d_in[8];
  const float* W2s   = (const float*)d_in[9];
  const float* W2v   = (const float*)d_in[10];
  const float* Wsc_s = (const float*)d_in[11];
  const float* Wsc_v = (const float*)d_in[12];
  float* out = (float*)d_out;

  int N = in_sizes[0]/128;
  int E = in_sizes[2]/8;
  int NB16 = (E + 15)/16;

  char* ws = (char*)d_ws;
  size_t off = 0;
  unsigned short* sv = (unsigned short*)(ws + off); off += (size_t)N*128*2;
  unsigned short* wper = (unsigned short*)(ws + off); off += (size_t)NB16*16*128*2;
  unsigned short* edata = (unsigned short*)(ws + off); off += (size_t)NB16*16*32;  // 32B records
  int* cnt    = (int*)(ws + off);             off += (size_t)N*4;
  int* offs   = (int*)(ws + off);             off += (size_t)(N+1)*4;
  int* cursor = (int*)(ws + off);             off += (size_t)N*4;
  int* bsum   = (int*)(ws + off);             off += 4096;
  unsigned short* wr1frag = (unsigned short*)(ws + off); off += 16384;
  float* wr0p = (float*)(ws + off);           off += 2048;
  unsigned short* wscfrag = (unsigned short*)(ws + off); off += 65536;
  unsigned short* w1frag = (unsigned short*)(ws + off);  off += 4096;

  int NB = (N + 1023)/1024;

  (void)hipMemsetAsync(cnt, 0, (size_t)N*4, stream);
  k_count_prep<<<dim3((E+255)/256), dim3(256), 0, stream>>>(eidx, E, cnt, Wr0, Wr1,
                                                            Wsc_s, Wsc_v, W1s, W1v,
                                                            wr1frag, wr0p, wscfrag, w1frag);
  k_scan_a <<<dim3(NB),          dim3(1024),0, stream>>>(cnt, N, offs, bsum);
  k_scan_b <<<dim3(1),           dim3(64),  0, stream>>>(bsum, NB, offs, N);
  k_scan_c <<<dim3(NB),          dim3(1024),0, stream>>>(offs, bsum, cursor, N);
  k_perm   <<<dim3((E+255)/256), dim3(256), 0, stream>>>(eemb, eattr, eidx, E, cursor, edata);
  k_node   <<<dim3((N+63)/64),   dim3(256), 0, stream>>>(nf, na, w1frag, wscfrag, sv, out, N);
  k_wedge  <<<dim3((NB16+3)/4),  dim3(256), 0, stream>>>(edata, wr1frag, wr0p, wper, NB16, E);
  k_msg    <<<dim3((N+3)/4),     dim3(256), 0, stream>>>(sv, wper, edata, offs,
                                                         W2s, W2v, out, N);
}

// Round 21
// 317.183 us; speedup vs baseline: 1.0298x; 1.0298x over previous
//
#include <hip/hip_runtime.h>
#include <stdint.h>
#include <math.h>

typedef __attribute__((ext_vector_type(8))) short bf16x8;
typedef __attribute__((ext_vector_type(4))) float f32x4;
typedef __attribute__((ext_vector_type(4))) unsigned int u32x4;
typedef __attribute__((ext_vector_type(4))) unsigned short us16x4;

__device__ __forceinline__ unsigned short f2bf(float f){
  unsigned int u = __float_as_uint(f);
  u += 0x7fffu + ((u >> 16) & 1u);   // RNE
  return (unsigned short)(u >> 16);
}

__device__ __forceinline__ float bf2f(short s){
  return __uint_as_float(((unsigned int)(unsigned short)s) << 16);
}

// ssp(x) = softplus(x) - ln2 = max(x,0) + ln2*(log2(1 + 2^(-|x|*log2e)) - 1)
__device__ __forceinline__ float ssp_f(float x){
  float u = exp2f(-fabsf(x)*1.4426950408889634f);
  return fmaxf(x, 0.f) + 0.6931471805599453f*(__log2f(1.0f + u) - 1.0f);
}

// ---------------- count + fused weight prep ----------------
__global__ void k_count_prep(const int* __restrict__ eidx, int E, int* __restrict__ cnt,
                             const float* __restrict__ Wr0, const float* __restrict__ Wr1,
                             const float* __restrict__ Wsc_s, const float* __restrict__ Wsc_v,
                             const float* __restrict__ W1s, const float* __restrict__ W1v,
                             unsigned short* __restrict__ wr1frag, float* __restrict__ wr0p,
                             unsigned short* __restrict__ wscfrag, unsigned short* __restrict__ w1frag){
  int id = blockIdx.x*256 + threadIdx.x;
  if(id < 512) wr0p[id] = Wr0[(id & 7)*64 + (id >> 3)];
  if(id < 1024){
    int fi = id >> 6, lane = id & 63;
    int c0 = lane & 15, g = lane >> 4;
    int kt = fi >> 3, ct = fi & 7;
    unsigned short tmp[8];
    #pragma unroll
    for(int i = 0; i < 8; i++){
      int k = kt*32 + g*8 + i;
      tmp[i] = f2bf(Wr1[k*128 + ct*16 + c0]);
    }
    #pragma unroll
    for(int i = 0; i < 8; i++) wr1frag[id*8 + i] = tmp[i];
  }
  if(id < 4096){
    int sel  = id >> 11;
    int fi   = (id >> 6) & 31;
    int lane = id & 63;
    int c0 = lane & 15, g = lane >> 4;
    int ks = fi >> 1, ct = fi & 1;
    const float* W = sel ? Wsc_v : Wsc_s;
    bf16x8 tmp;
    #pragma unroll
    for(int i = 0; i < 8; i++){
      int k = ks*32 + g*8 + i;
      tmp[i] = (short)f2bf(W[k*32 + ct*16 + c0]);
    }
    *(bf16x8*)&wscfrag[(size_t)id*8] = tmp;
  }
  if(id < 256){
    int sel = id >> 7, ct = (id >> 6) & 1, lane = id & 63;
    int c0 = lane & 15, g = lane >> 4;
    const float* W = sel ? W1v : W1s;
    bf16x8 tmp;
    #pragma unroll
    for(int i = 0; i < 8; i++){
      int m = g*8 + i;
      tmp[i] = (short)f2bf(W[m*32 + ct*16 + c0]);
    }
    *(bf16x8*)&w1frag[(size_t)id*8] = tmp;
  }
  if(id < E) atomicAdd(&cnt[eidx[E + id]], 1);
}

// ---------------- CSR scan (parallel multi-block, round-5-validated) ----------------
__global__ void k_scan_a(const int* __restrict__ cnt, int N, int* __restrict__ offs, int* __restrict__ bsum){
  __shared__ int arr[1024];
  int t = threadIdx.x, i = blockIdx.x*1024 + t;
  int v = (i < N) ? cnt[i] : 0;
  int own = v;
  arr[t] = v;
  for(int off = 1; off < 1024; off <<= 1){
    __syncthreads();
    int u = (t >= off) ? arr[t - off] : 0;
    __syncthreads();
    arr[t] += u;
  }
  if(i < N) offs[i] = arr[t] - own;
  if(t == 1023) bsum[blockIdx.x] = arr[1023];
}

__global__ void k_scan_b(int* __restrict__ bsum, int NB, int* __restrict__ offs, int N){
  if(threadIdx.x == 0 && blockIdx.x == 0){
    int run = 0;
    for(int b = 0; b < NB; b++){ int t = bsum[b]; bsum[b] = run; run += t; }
    offs[N] = run;
  }
}

__global__ void k_scan_c(int* __restrict__ offs, const int* __restrict__ bsum, int* __restrict__ cursor, int N){
  int i = blockIdx.x*1024 + threadIdx.x;
  if(i < N){
    int v = offs[i] + bsum[blockIdx.x];
    offs[i] = v;
    cursor[i] = v;
  }
}

// permute edges into CSR order, packed 32B record per edge:
// bytes 0-15: eemb bf16x8; 16-23: eattr bf16x4; 24-27: src; 28-31 pad.
__global__ void k_perm(const float* __restrict__ eemb, const float* __restrict__ eattr,
                       const int* __restrict__ eidx, int E, int* __restrict__ cursor,
                       unsigned short* __restrict__ edata){
  int e = blockIdx.x*256 + threadIdx.x;
  if(e < E){
    int d = eidx[E + e];
    int dp = atomicAdd(&cursor[d], 1);
    f32x4 a = *(const f32x4*)(eemb + (size_t)e*8);
    f32x4 b = *(const f32x4*)(eemb + (size_t)e*8 + 4);
    bf16x8 pk;
    pk[0] = (short)f2bf(a[0]); pk[1] = (short)f2bf(a[1]);
    pk[2] = (short)f2bf(a[2]); pk[3] = (short)f2bf(a[3]);
    pk[4] = (short)f2bf(b[0]); pk[5] = (short)f2bf(b[1]);
    pk[6] = (short)f2bf(b[2]); pk[7] = (short)f2bf(b[3]);
    f32x4 ea = *(const f32x4*)(eattr + (size_t)e*4);
    unsigned int i0 = (unsigned int)f2bf(ea[0]) | ((unsigned int)f2bf(ea[1]) << 16);
    unsigned int i1 = (unsigned int)f2bf(ea[2]) | ((unsigned int)f2bf(ea[3]) << 16);
    u32x4 hi = { i0, i1, (unsigned int)eidx[e], 0u };
    *(bf16x8*)(edata + (size_t)dp*16) = pk;
    *(u32x4*)(edata + (size_t)dp*16 + 8) = hi;
  }
}

// ---------------- node kernel: sv via MFMA (bf16, swizzled layout) + self-connection ----------------
__global__ __launch_bounds__(256) void k_node(
    const float* __restrict__ nf, const float* __restrict__ na,
    const unsigned short* __restrict__ w1frag,
    const unsigned short* __restrict__ wscfrag,
    unsigned short* __restrict__ sv, float* __restrict__ out, int N)
{
  __shared__ float xl[64*133];
  __shared__ __align__(16) float al[64*20];
  const int t = threadIdx.x;
  const int n0 = blockIdx.x*64;

  for(int idx = t; idx < 64*128; idx += 256){
    int r = idx >> 7, c = idx & 127;
    int n = n0 + r;
    xl[r*133 + c] = (n < N) ? nf[(size_t)n*128 + c] : 0.f;
  }
  for(int idx = t; idx < 64*16; idx += 256){
    int r = idx >> 4, c = idx & 15;
    int n = n0 + r;
    al[r*20 + c] = (n < N) ? na[(size_t)n*16 + c] : 0.f;
  }
  __syncthreads();

  const float INVM = 0.17677669529663689f;   // 1/sqrt(32)
  const float FC   = 0.044194173824159216f;  // 1/sqrt(512)

  const int lane = t & 63, wv = t >> 6;
  const int c0 = lane & 15, g = lane >> 4;

  // ---- sv via MFMA ----
  {
    const unsigned short* w1f = w1frag + (size_t)((wv == 0) ? 0 : 1024);
    bf16x8 b0 = *(const bf16x8*)&w1f[(0*64 + lane)*8];
    bf16x8 b1 = *(const bf16x8*)&w1f[(1*64 + lane)*8];
    #pragma unroll
    for(int rt = 0; rt < 4; rt++){
      int row = rt*16 + c0;
      bf16x8 a;
      #pragma unroll
      for(int i = 0; i < 8; i++){
        int m = g*8 + i;
        float xv = (wv == 0) ? xl[row*133 + m] : xl[row*133 + 32 + 3*m + (wv-1)];
        a[i] = (short)f2bf(xv);
      }
      f32x4 z = {0.f,0.f,0.f,0.f};
      f32x4 d0 = __builtin_amdgcn_mfma_f32_16x16x32_bf16(a, b0, z, 0, 0, 0);
      f32x4 d1 = __builtin_amdgcn_mfma_f32_16x16x32_bf16(a, b1, z, 0, 0, 0);
      #pragma unroll
      for(int r = 0; r < 4; r++){
        int node = n0 + rt*16 + g*4 + r;
        if(node < N){
          sv[(size_t)node*128 + c0*8 + wv*2 + 0] = f2bf(d0[r]*INVM);
          sv[(size_t)node*128 + c0*8 + wv*2 + 1] = f2bf(d1[r]*INVM);
        }
      }
    }
  }

  // ---- self-connection MFMA ----
  const unsigned short* wf = wscfrag + (size_t)((wv == 0) ? 0 : 16384);

  f32x4 accm[4][2];
  #pragma unroll
  for(int rt = 0; rt < 4; rt++)
    #pragma unroll
    for(int ct = 0; ct < 2; ct++) accm[rt][ct] = (f32x4){0.f,0.f,0.f,0.f};

  for(int ks = 0; ks < 16; ks++){
    bf16x8 bfr[2];
    bfr[0] = *(const bf16x8*)&wf[(size_t)((ks*2 + 0)*64 + lane)*8];
    bfr[1] = *(const bf16x8*)&wf[(size_t)((ks*2 + 1)*64 + lane)*8];
    int u2 = ks*2 + (g >> 1);
    int ab = (g & 1)*8;
    #pragma unroll
    for(int rt = 0; rt < 4; rt++){
      int row = rt*16 + c0;
      float xv = (wv == 0) ? xl[row*133 + u2] : xl[row*133 + 32 + 3*u2 + (wv-1)];
      f32x4 v0 = *(const f32x4*)&al[row*20 + ab];
      f32x4 v1 = *(const f32x4*)&al[row*20 + ab + 4];
      bf16x8 a;
      a[0] = (short)f2bf(xv*v0[0]); a[1] = (short)f2bf(xv*v0[1]);
      a[2] = (short)f2bf(xv*v0[2]); a[3] = (short)f2bf(xv*v0[3]);
      a[4] = (short)f2bf(xv*v1[0]); a[5] = (short)f2bf(xv*v1[1]);
      a[6] = (short)f2bf(xv*v1[2]); a[7] = (short)f2bf(xv*v1[3]);
      #pragma unroll
      for(int ct = 0; ct < 2; ct++)
        accm[rt][ct] = __builtin_amdgcn_mfma_f32_16x16x32_bf16(a, bfr[ct], accm[rt][ct], 0, 0, 0);
    }
  }

  #pragma unroll
  for(int rt = 0; rt < 4; rt++)
    #pragma unroll
    for(int ct = 0; ct < 2; ct++)
      #pragma unroll
      for(int i = 0; i < 4; i++){
        int node = n0 + rt*16 + g*4 + i;
        if(node < N){
          int col = ct*16 + c0;
          float v = accm[rt][ct][i] * FC;
          if(wv == 0) out[(size_t)node*128 + col] = v;
          else        out[(size_t)node*128 + 32 + 3*col + (wv-1)] = v;
        }
      }
}

// ---------------- phase 1: w = (ssp(ee@Wr0)/sqrt8)@Wr1 * 1/8, CSR-ordered, bf16, col-swizzled ----
__global__ __launch_bounds__(256, 4) void k_wedge(
    const unsigned short* __restrict__ edata,
    const unsigned short* __restrict__ wr1frag, const float* __restrict__ wr0p,
    unsigned short* __restrict__ wper, int NB16, int E)
{
  __shared__ __align__(16) float wr0t[512];
  __shared__ __align__(16) unsigned short bwl[8192];
  const int t = threadIdx.x;
  {
    const f32x4* s4 = (const f32x4*)wr1frag;
    f32x4* d4 = (f32x4*)bwl;
    #pragma unroll
    for(int i = 0; i < 4; i++) d4[t + i*256] = s4[t + i*256];
    if(t < 128) ((f32x4*)wr0t)[t] = ((const f32x4*)wr0p)[t];
  }
  __syncthreads();

  const int lane = t & 63;
  const int wv   = t >> 6;
  const int c0   = lane & 15;
  const int g    = lane >> 4;
  const float S8 = 0.35355339059327373f;   // 1/sqrt(8)

  int p = blockIdx.x*4 + wv;
  if(p >= NB16) return;
  int p16 = p*16;
  int bc = E - p16; if(bc > 16) bc = 16;
  bool val = (c0 < bc);

  bf16x8 eb8 = *(const bf16x8*)(edata + (size_t)(p16 + (val ? c0 : 0))*16);
  float ee[8];
  #pragma unroll
  for(int i = 0; i < 8; i++) ee[i] = bf2f(eb8[i]);

  bf16x8 afr[2];
  #pragma unroll
  for(int kt = 0; kt < 2; kt++){
    bf16x8 a;
    #pragma unroll
    for(int i = 0; i < 8; i++){
      int j = kt*32 + g*8 + i;
      f32x4 wa = *(const f32x4*)&wr0t[j*8];
      f32x4 wb = *(const f32x4*)&wr0t[j*8 + 4];
      float pre = ee[0]*wa[0] + ee[1]*wa[1] + ee[2]*wa[2] + ee[3]*wa[3]
                + ee[4]*wb[0] + ee[5]*wb[1] + ee[6]*wb[2] + ee[7]*wb[3];
      a[i] = (short)f2bf(ssp_f(pre * S8));
    }
    afr[kt] = a;
  }

  f32x4 cfr[8];
  #pragma unroll
  for(int ct = 0; ct < 8; ct++) cfr[ct] = (f32x4){0.f,0.f,0.f,0.f};
  #pragma unroll
  for(int kt = 0; kt < 2; kt++)
    #pragma unroll
    for(int ct = 0; ct < 8; ct++){
      bf16x8 bfr = *(const bf16x8*)&bwl[((kt*8 + ct)*64 + lane)*8];
      cfr[ct] = __builtin_amdgcn_mfma_f32_16x16x32_bf16(afr[kt], bfr, cfr[ct], 0, 0, 0);
    }

  #pragma unroll
  for(int i = 0; i < 4; i++){
    if(g*4 + i < bc){
      bf16x8 wpk;
      #pragma unroll
      for(int ct = 0; ct < 8; ct++) wpk[ct] = (short)f2bf(cfr[ct][i] * 0.125f);
      *(bf16x8*)(wper + (size_t)(p16 + g*4 + i)*128 + c0*8) = wpk;
    }
  }
}

// ---------------- phase 2: node-centric gather + messages + bf16-W2 vectorized epilogue ----------------
// Batch loads 3-phase split (issue-all, gather-all, compute) to overlap the 4
// independent sv-gather chains per 16-edge batch (VGPR 32 serialized them).
__global__ __launch_bounds__(256, 4) void k_msg(
    const unsigned short* __restrict__ sv, const unsigned short* __restrict__ wper,
    const unsigned short* __restrict__ edata, const int* __restrict__ offs,
    const float* __restrict__ W2s, const float* __restrict__ W2v,
    float* __restrict__ out, int N)
{
  __shared__ __align__(16) float nsl[4][256];          // [0..63]=ns, [64+c*64+m]=nv[c][m]
  __shared__ __align__(8) unsigned short w2sTb[32*68]; // w2sTb[o*68+m] = bf16(W2s[m][o])
  __shared__ __align__(8) unsigned short w2vTb[32*68]; // w2vTb[o*68+m] = bf16(W2v[m][o])
  const int t = threadIdx.x, lane = t & 63, wv = t >> 6;
  const int c0 = lane & 15, g = lane >> 4;

  {
    #pragma unroll
    for(int i = 0; i < 8; i++){
      int idx = t + i*256;          // 0..2047
      int m = idx >> 5, o = idx & 31;
      w2sTb[o*68 + m] = f2bf(W2s[idx]);
      w2vTb[o*68 + m] = f2bf(W2v[idx]);
    }
  }
  __syncthreads();

  const int n = blockIdx.x*4 + wv;
  if(n >= N) return;

  const float SC2 = 0.03125f;              // (1/sqrt64)*(1/sqrt16)
  const float IS3 = 0.57735026918962576f;  // 1/sqrt(3)

  float acc[16];
  #pragma unroll
  for(int i = 0; i < 16; i++) acc[i] = 0.f;

  const int eb0 = offs[n], eb1 = offs[n+1];
  for(int eb = eb0; eb < eb1; eb += 16){
    int bc = eb1 - eb; if(bc > 16) bc = 16;

    // phase 1: issue all independent loads (clamped tail indices re-read slot-0's line)
    u32x4  rec0, rec1, rec2, rec3;
    bf16x8 w80, w81, w82, w83;
    {
      int e0i = eb + ((0*4 + g) < bc ? (0*4 + g) : 0);
      int e1i = eb + ((1*4 + g) < bc ? (1*4 + g) : 0);
      int e2i = eb + ((2*4 + g) < bc ? (2*4 + g) : 0);
      int e3i = eb + ((3*4 + g) < bc ? (3*4 + g) : 0);
      rec0 = *(const u32x4*)(edata + (size_t)e0i*16 + 8);
      rec1 = *(const u32x4*)(edata + (size_t)e1i*16 + 8);
      rec2 = *(const u32x4*)(edata + (size_t)e2i*16 + 8);
      rec3 = *(const u32x4*)(edata + (size_t)e3i*16 + 8);
      w80 = *(const bf16x8*)(wper + (size_t)e0i*128 + c0*8);
      w81 = *(const bf16x8*)(wper + (size_t)e1i*128 + c0*8);
      w82 = *(const bf16x8*)(wper + (size_t)e2i*128 + c0*8);
      w83 = *(const bf16x8*)(wper + (size_t)e3i*128 + c0*8);
    }
    // phase 2: dependent sv gathers, 4 chains in flight
    bf16x8 sr0 = *(const bf16x8*)(sv + (size_t)(int)rec0.z*128 + c0*8);
    bf16x8 sr1 = *(const bf16x8*)(sv + (size_t)(int)rec1.z*128 + c0*8);
    bf16x8 sr2 = *(const bf16x8*)(sv + (size_t)(int)rec2.z*128 + c0*8);
    bf16x8 sr3 = *(const bf16x8*)(sv + (size_t)(int)rec3.z*128 + c0*8);

    // phase 3: predicated math
    #pragma unroll
    for(int r = 0; r < 4; r++){
      int es = r*4 + g;
      if(es >= bc) continue;
      u32x4  rec = (r == 0) ? rec0 : (r == 1) ? rec1 : (r == 2) ? rec2 : rec3;
      bf16x8 w8  = (r == 0) ? w80  : (r == 1) ? w81  : (r == 2) ? w82  : w83;
      bf16x8 sr  = (r == 0) ? sr0  : (r == 1) ? sr1  : (r == 2) ? sr2  : sr3;
      float e0  = bf2f((short)(rec.x & 0xffff));
      float e1x = bf2f((short)(rec.x >> 16));
      float e1y = bf2f((short)(rec.y & 0xffff));
      float e1z = bf2f((short)(rec.y >> 16));
      float w0A = bf2f(w8[0]), w0B = bf2f(w8[1]);
      float w1A = bf2f(w8[2]), w1B = bf2f(w8[3]);
      float w2A = bf2f(w8[4]), w2B = bf2f(w8[5]);
      float w3A = bf2f(w8[6]), w3B = bf2f(w8[7]);
      float ssA = bf2f(sr[0]), ssB = bf2f(sr[1]);
      float vA0 = bf2f(sr[2]), vB0 = bf2f(sr[3]);
      float vA1 = bf2f(sr[4]), vB1 = bf2f(sr[5]);
      float vA2 = bf2f(sr[6]), vB2 = bf2f(sr[7]);

      acc[0] += w0A*ssA*e0;
      acc[1] += w0B*ssB*e0;
      acc[2] += w3A*(vA0*e1x + vA1*e1y + vA2*e1z);
      acc[3] += w3B*(vB0*e1x + vB1*e1y + vB2*e1z);
      float h1A = w1A*ssA, h1B = w1B*ssB;
      acc[4]  += h1A*e1x; acc[5]  += h1A*e1y; acc[6]  += h1A*e1z;
      acc[7]  += h1B*e1x; acc[8]  += h1B*e1y; acc[9]  += h1B*e1z;
      float h2A = w2A*e0, h2B = w2B*e0;
      acc[10] += h2A*vA0; acc[11] += h2A*vA1; acc[12] += h2A*vA2;
      acc[13] += h2B*vB0; acc[14] += h2B*vB1; acc[15] += h2B*vB2;
    }
  }

  #pragma unroll
  for(int i = 0; i < 16; i++){
    acc[i] += __shfl_xor(acc[i], 16);
    acc[i] += __shfl_xor(acc[i], 32);
  }

  float* nl = nsl[wv];
  if(g == 0){
    nl[c0]      = acc[0];
    nl[16 + c0] = acc[1];
    nl[32 + c0] = acc[2]*IS3;
    nl[48 + c0] = acc[3]*IS3;
    #pragma unroll
    for(int cc = 0; cc < 3; cc++){
      nl[64 + cc*64 +  0 + c0] = acc[4  + cc];
      nl[64 + cc*64 + 16 + c0] = acc[7  + cc];
      nl[64 + cc*64 + 32 + c0] = acc[10 + cc];
      nl[64 + cc*64 + 48 + c0] = acc[13 + cc];
    }
  }
  __threadfence_block();

  const int t1 = lane, t2 = 64 + lane;
  int u1 = t1 - 32; if(u1 < 0) u1 = 0;
  const int w1i = u1/3, c1i = u1%3;
  const int w2i = (t2 - 32)/3, c2i = (t2 - 32)%3;
  const f32x4*  p1a = (const f32x4*)((t1 < 32) ? &nl[0] : &nl[64 + c1i*64]);
  const us16x4* p1b = (const us16x4*)((t1 < 32) ? &w2sTb[t1*68] : &w2vTb[w1i*68]);
  const f32x4*  p2a = (const f32x4*)&nl[64 + c2i*64];
  const us16x4* p2b = (const us16x4*)&w2vTb[w2i*68];
  float s1 = 0.f, s2 = 0.f;
  #pragma unroll
  for(int q = 0; q < 16; q++){
    f32x4 a = p1a[q];
    us16x4 b = p1b[q];
    f32x4 c = p2a[q];
    us16x4 d = p2b[q];
    s1 += a[0]*bf2f((short)b[0]) + a[1]*bf2f((short)b[1])
        + a[2]*bf2f((short)b[2]) + a[3]*bf2f((short)b[3]);
    s2 += c[0]*bf2f((short)d[0]) + c[1]*bf2f((short)d[1])
        + c[2]*bf2f((short)d[2]) + c[3]*bf2f((short)d[3]);
  }
  out[(size_t)n*128 + t1] += s1*SC2;
  out[(size_t)n*128 + t2] += s2*SC2;
}

extern "C" void kernel_launch(void* const* d_in, const int* in_sizes, int n_in,
                              void* d_out, int out_size, void* d_ws, size_t ws_size,
                              hipStream_t stream)
{
  const float* nf    = (const float*)d_in[0];
  const float* na    = (const float*)d_in[1];
  const float* eemb  = (const float*)d_in[2];
  const float* eattr = (const float*)d_in[3];
  const int*   eidx  = (const int*)d_in[4];
  const float* W1s   = (const float*)d_in[5];
  const float* W1v   = (const float*)d_in[6];
  const float* Wr0   = (const float*)d_in[7];
  const float* Wr1   = (const float*)d_in[8];
  const float* W2s   = (const float*)d_in[9];
  const float* W2v   = (const float*)d_in[10];
  const float* Wsc_s = (const float*)d_in[11];
  const float* Wsc_v = (const float*)d_in[12];
  float* out = (float*)d_out;

  int N = in_sizes[0]/128;
  int E = in_sizes[2]/8;
  int NB16 = (E + 15)/16;

  char* ws = (char*)d_ws;
  size_t off = 0;
  unsigned short* sv = (unsigned short*)(ws + off); off += (size_t)N*128*2;
  unsigned short* wper = (unsigned short*)(ws + off); off += (size_t)NB16*16*128*2;
  unsigned short* edata = (unsigned short*)(ws + off); off += (size_t)NB16*16*32;  // 32B records
  int* cnt    = (int*)(ws + off);             off += (size_t)N*4;
  int* offs   = (int*)(ws + off);             off += (size_t)(N+1)*4;
  int* cursor = (int*)(ws + off);             off += (size_t)N*4;
  int* bsum   = (int*)(ws + off);             off += 4096;
  unsigned short* wr1frag = (unsigned short*)(ws + off); off += 16384;
  float* wr0p = (float*)(ws + off);           off += 2048;
  unsigned short* wscfrag = (unsigned short*)(ws + off); off += 65536;
  unsigned short* w1frag = (unsigned short*)(ws + off);  off += 4096;

  int NB = (N + 1023)/1024;

  (void)hipMemsetAsync(cnt, 0, (size_t)N*4, stream);
  k_count_prep<<<dim3((E+255)/256), dim3(256), 0, stream>>>(eidx, E, cnt, Wr0, Wr1,
                                                            Wsc_s, Wsc_v, W1s, W1v,
                                                            wr1frag, wr0p, wscfrag, w1frag);
  k_scan_a <<<dim3(NB),          dim3(1024),0, stream>>>(cnt, N, offs, bsum);
  k_scan_b <<<dim3(1),           dim3(64),  0, stream>>>(bsum, NB, offs, N);
  k_scan_c <<<dim3(NB),          dim3(1024),0, stream>>>(offs, bsum, cursor, N);
  k_perm   <<<dim3((E+255)/256), dim3(256), 0, stream>>>(eemb, eattr, eidx, E, cursor, edata);
  k_node   <<<dim3((N+63)/64),   dim3(256), 0, stream>>>(nf, na, w1frag, wscfrag, sv, out, N);
  k_wedge  <<<dim3((NB16+3)/4),  dim3(256), 0, stream>>>(edata, wr1frag, wr0p, wper, NB16, E);
  k_msg    <<<dim3((N+3)/4),     dim3(256), 0, stream>>>(sv, wper, edata, offs,
                                                         W2s, W2v, out, N);
}

// Round 22
// 312.835 us; speedup vs baseline: 1.0441x; 1.0139x over previous
//
#include <hip/hip_runtime.h>
#include <stdint.h>
#include <math.h>

typedef __attribute__((ext_vector_type(8))) short bf16x8;
typedef __attribute__((ext_vector_type(4))) float f32x4;
typedef __attribute__((ext_vector_type(4))) unsigned int u32x4;
typedef __attribute__((ext_vector_type(4))) unsigned short us16x4;

__device__ __forceinline__ unsigned short f2bf(float f){
  unsigned int u = __float_as_uint(f);
  u += 0x7fffu + ((u >> 16) & 1u);   // RNE
  return (unsigned short)(u >> 16);
}

__device__ __forceinline__ float bf2f(short s){
  return __uint_as_float(((unsigned int)(unsigned short)s) << 16);
}

// ssp(x) = softplus(x) - ln2 = max(x,0) + ln2*(log2(1 + 2^(-|x|*log2e)) - 1)
__device__ __forceinline__ float ssp_f(float x){
  float u = exp2f(-fabsf(x)*1.4426950408889634f);
  return fmaxf(x, 0.f) + 0.6931471805599453f*(__log2f(1.0f + u) - 1.0f);
}

// ---------------- count + fused weight prep ----------------
__global__ void k_count_prep(const int* __restrict__ eidx, int E, int* __restrict__ cnt,
                             const float* __restrict__ Wr0, const float* __restrict__ Wr1,
                             const float* __restrict__ Wsc_s, const float* __restrict__ Wsc_v,
                             const float* __restrict__ W1s, const float* __restrict__ W1v,
                             unsigned short* __restrict__ wr1frag, float* __restrict__ wr0p,
                             unsigned short* __restrict__ wscfrag, unsigned short* __restrict__ w1frag){
  int id = blockIdx.x*256 + threadIdx.x;
  if(id < 512) wr0p[id] = Wr0[(id & 7)*64 + (id >> 3)];
  if(id < 1024){
    int fi = id >> 6, lane = id & 63;
    int c0 = lane & 15, g = lane >> 4;
    int kt = fi >> 3, ct = fi & 7;
    unsigned short tmp[8];
    #pragma unroll
    for(int i = 0; i < 8; i++){
      int k = kt*32 + g*8 + i;
      tmp[i] = f2bf(Wr1[k*128 + ct*16 + c0]);
    }
    #pragma unroll
    for(int i = 0; i < 8; i++) wr1frag[id*8 + i] = tmp[i];
  }
  if(id < 4096){
    int sel  = id >> 11;
    int fi   = (id >> 6) & 31;
    int lane = id & 63;
    int c0 = lane & 15, g = lane >> 4;
    int ks = fi >> 1, ct = fi & 1;
    const float* W = sel ? Wsc_v : Wsc_s;
    bf16x8 tmp;
    #pragma unroll
    for(int i = 0; i < 8; i++){
      int k = ks*32 + g*8 + i;
      tmp[i] = (short)f2bf(W[k*32 + ct*16 + c0]);
    }
    *(bf16x8*)&wscfrag[(size_t)id*8] = tmp;
  }
  if(id < 256){
    int sel = id >> 7, ct = (id >> 6) & 1, lane = id & 63;
    int c0 = lane & 15, g = lane >> 4;
    const float* W = sel ? W1v : W1s;
    bf16x8 tmp;
    #pragma unroll
    for(int i = 0; i < 8; i++){
      int m = g*8 + i;
      tmp[i] = (short)f2bf(W[m*32 + ct*16 + c0]);
    }
    *(bf16x8*)&w1frag[(size_t)id*8] = tmp;
  }
  if(id < E) atomicAdd(&cnt[eidx[E + id]], 1);
}

// ---------------- CSR scan (parallel multi-block, round-5-validated) ----------------
__global__ void k_scan_a(const int* __restrict__ cnt, int N, int* __restrict__ offs, int* __restrict__ bsum){
  __shared__ int arr[1024];
  int t = threadIdx.x, i = blockIdx.x*1024 + t;
  int v = (i < N) ? cnt[i] : 0;
  int own = v;
  arr[t] = v;
  for(int off = 1; off < 1024; off <<= 1){
    __syncthreads();
    int u = (t >= off) ? arr[t - off] : 0;
    __syncthreads();
    arr[t] += u;
  }
  if(i < N) offs[i] = arr[t] - own;
  if(t == 1023) bsum[blockIdx.x] = arr[1023];
}

__global__ void k_scan_b(int* __restrict__ bsum, int NB, int* __restrict__ offs, int N){
  if(threadIdx.x == 0 && blockIdx.x == 0){
    int run = 0;
    for(int b = 0; b < NB; b++){ int t = bsum[b]; bsum[b] = run; run += t; }
    offs[N] = run;
  }
}

__global__ void k_scan_c(int* __restrict__ offs, const int* __restrict__ bsum, int* __restrict__ cursor, int N){
  int i = blockIdx.x*1024 + threadIdx.x;
  if(i < N){
    int v = offs[i] + bsum[blockIdx.x];
    offs[i] = v;
    cursor[i] = v;
  }
}

// permute edges into CSR order, packed 32B record per edge:
// bytes 0-15: eemb bf16x8; 16-23: eattr bf16x4; 24-27: src; 28-31 pad.
__global__ void k_perm(const float* __restrict__ eemb, const float* __restrict__ eattr,
                       const int* __restrict__ eidx, int E, int* __restrict__ cursor,
                       unsigned short* __restrict__ edata){
  int e = blockIdx.x*256 + threadIdx.x;
  if(e < E){
    int d = eidx[E + e];
    int dp = atomicAdd(&cursor[d], 1);
    f32x4 a = *(const f32x4*)(eemb + (size_t)e*8);
    f32x4 b = *(const f32x4*)(eemb + (size_t)e*8 + 4);
    bf16x8 pk;
    pk[0] = (short)f2bf(a[0]); pk[1] = (short)f2bf(a[1]);
    pk[2] = (short)f2bf(a[2]); pk[3] = (short)f2bf(a[3]);
    pk[4] = (short)f2bf(b[0]); pk[5] = (short)f2bf(b[1]);
    pk[6] = (short)f2bf(b[2]); pk[7] = (short)f2bf(b[3]);
    f32x4 ea = *(const f32x4*)(eattr + (size_t)e*4);
    unsigned int i0 = (unsigned int)f2bf(ea[0]) | ((unsigned int)f2bf(ea[1]) << 16);
    unsigned int i1 = (unsigned int)f2bf(ea[2]) | ((unsigned int)f2bf(ea[3]) << 16);
    u32x4 hi = { i0, i1, (unsigned int)eidx[e], 0u };
    *(bf16x8*)(edata + (size_t)dp*16) = pk;
    *(u32x4*)(edata + (size_t)dp*16 + 8) = hi;
  }
}

// ---------------- node kernel: sv via MFMA (bf16, swizzled layout) + self-connection ----------------
__global__ __launch_bounds__(256) void k_node(
    const float* __restrict__ nf, const float* __restrict__ na,
    const unsigned short* __restrict__ w1frag,
    const unsigned short* __restrict__ wscfrag,
    unsigned short* __restrict__ sv, float* __restrict__ out, int N)
{
  __shared__ float xl[64*133];
  __shared__ __align__(16) float al[64*20];
  const int t = threadIdx.x;
  const int n0 = blockIdx.x*64;

  for(int idx = t; idx < 64*128; idx += 256){
    int r = idx >> 7, c = idx & 127;
    int n = n0 + r;
    xl[r*133 + c] = (n < N) ? nf[(size_t)n*128 + c] : 0.f;
  }
  for(int idx = t; idx < 64*16; idx += 256){
    int r = idx >> 4, c = idx & 15;
    int n = n0 + r;
    al[r*20 + c] = (n < N) ? na[(size_t)n*16 + c] : 0.f;
  }
  __syncthreads();

  const float INVM = 0.17677669529663689f;   // 1/sqrt(32)
  const float FC   = 0.044194173824159216f;  // 1/sqrt(512)

  const int lane = t & 63, wv = t >> 6;
  const int c0 = lane & 15, g = lane >> 4;

  // ---- sv via MFMA ----
  {
    const unsigned short* w1f = w1frag + (size_t)((wv == 0) ? 0 : 1024);
    bf16x8 b0 = *(const bf16x8*)&w1f[(0*64 + lane)*8];
    bf16x8 b1 = *(const bf16x8*)&w1f[(1*64 + lane)*8];
    #pragma unroll
    for(int rt = 0; rt < 4; rt++){
      int row = rt*16 + c0;
      bf16x8 a;
      #pragma unroll
      for(int i = 0; i < 8; i++){
        int m = g*8 + i;
        float xv = (wv == 0) ? xl[row*133 + m] : xl[row*133 + 32 + 3*m + (wv-1)];
        a[i] = (short)f2bf(xv);
      }
      f32x4 z = {0.f,0.f,0.f,0.f};
      f32x4 d0 = __builtin_amdgcn_mfma_f32_16x16x32_bf16(a, b0, z, 0, 0, 0);
      f32x4 d1 = __builtin_amdgcn_mfma_f32_16x16x32_bf16(a, b1, z, 0, 0, 0);
      #pragma unroll
      for(int r = 0; r < 4; r++){
        int node = n0 + rt*16 + g*4 + r;
        if(node < N){
          sv[(size_t)node*128 + c0*8 + wv*2 + 0] = f2bf(d0[r]*INVM);
          sv[(size_t)node*128 + c0*8 + wv*2 + 1] = f2bf(d1[r]*INVM);
        }
      }
    }
  }

  // ---- self-connection MFMA ----
  const unsigned short* wf = wscfrag + (size_t)((wv == 0) ? 0 : 16384);

  f32x4 accm[4][2];
  #pragma unroll
  for(int rt = 0; rt < 4; rt++)
    #pragma unroll
    for(int ct = 0; ct < 2; ct++) accm[rt][ct] = (f32x4){0.f,0.f,0.f,0.f};

  for(int ks = 0; ks < 16; ks++){
    bf16x8 bfr[2];
    bfr[0] = *(const bf16x8*)&wf[(size_t)((ks*2 + 0)*64 + lane)*8];
    bfr[1] = *(const bf16x8*)&wf[(size_t)((ks*2 + 1)*64 + lane)*8];
    int u2 = ks*2 + (g >> 1);
    int ab = (g & 1)*8;
    #pragma unroll
    for(int rt = 0; rt < 4; rt++){
      int row = rt*16 + c0;
      float xv = (wv == 0) ? xl[row*133 + u2] : xl[row*133 + 32 + 3*u2 + (wv-1)];
      f32x4 v0 = *(const f32x4*)&al[row*20 + ab];
      f32x4 v1 = *(const f32x4*)&al[row*20 + ab + 4];
      bf16x8 a;
      a[0] = (short)f2bf(xv*v0[0]); a[1] = (short)f2bf(xv*v0[1]);
      a[2] = (short)f2bf(xv*v0[2]); a[3] = (short)f2bf(xv*v0[3]);
      a[4] = (short)f2bf(xv*v1[0]); a[5] = (short)f2bf(xv*v1[1]);
      a[6] = (short)f2bf(xv*v1[2]); a[7] = (short)f2bf(xv*v1[3]);
      #pragma unroll
      for(int ct = 0; ct < 2; ct++)
        accm[rt][ct] = __builtin_amdgcn_mfma_f32_16x16x32_bf16(a, bfr[ct], accm[rt][ct], 0, 0, 0);
    }
  }

  #pragma unroll
  for(int rt = 0; rt < 4; rt++)
    #pragma unroll
    for(int ct = 0; ct < 2; ct++)
      #pragma unroll
      for(int i = 0; i < 4; i++){
        int node = n0 + rt*16 + g*4 + i;
        if(node < N){
          int col = ct*16 + c0;
          float v = accm[rt][ct][i] * FC;
          if(wv == 0) out[(size_t)node*128 + col] = v;
          else        out[(size_t)node*128 + 32 + 3*col + (wv-1)] = v;
        }
      }
}

// ---------------- phase 1: w = (ssp(ee@Wr0)/sqrt8)@Wr1 * 1/8, CSR-ordered, bf16, col-swizzled ----
__global__ __launch_bounds__(256, 4) void k_wedge(
    const unsigned short* __restrict__ edata,
    const unsigned short* __restrict__ wr1frag, const float* __restrict__ wr0p,
    unsigned short* __restrict__ wper, int NB16, int E)
{
  __shared__ __align__(16) float wr0t[512];
  __shared__ __align__(16) unsigned short bwl[8192];
  const int t = threadIdx.x;
  {
    const f32x4* s4 = (const f32x4*)wr1frag;
    f32x4* d4 = (f32x4*)bwl;
    #pragma unroll
    for(int i = 0; i < 4; i++) d4[t + i*256] = s4[t + i*256];
    if(t < 128) ((f32x4*)wr0t)[t] = ((const f32x4*)wr0p)[t];
  }
  __syncthreads();

  const int lane = t & 63;
  const int wv   = t >> 6;
  const int c0   = lane & 15;
  const int g    = lane >> 4;
  const float S8 = 0.35355339059327373f;   // 1/sqrt(8)

  int p = blockIdx.x*4 + wv;
  if(p >= NB16) return;
  int p16 = p*16;
  int bc = E - p16; if(bc > 16) bc = 16;
  bool val = (c0 < bc);

  bf16x8 eb8 = *(const bf16x8*)(edata + (size_t)(p16 + (val ? c0 : 0))*16);
  float ee[8];
  #pragma unroll
  for(int i = 0; i < 8; i++) ee[i] = bf2f(eb8[i]);

  bf16x8 afr[2];
  #pragma unroll
  for(int kt = 0; kt < 2; kt++){
    bf16x8 a;
    #pragma unroll
    for(int i = 0; i < 8; i++){
      int j = kt*32 + g*8 + i;
      f32x4 wa = *(const f32x4*)&wr0t[j*8];
      f32x4 wb = *(const f32x4*)&wr0t[j*8 + 4];
      float pre = ee[0]*wa[0] + ee[1]*wa[1] + ee[2]*wa[2] + ee[3]*wa[3]
                + ee[4]*wb[0] + ee[5]*wb[1] + ee[6]*wb[2] + ee[7]*wb[3];
      a[i] = (short)f2bf(ssp_f(pre * S8));
    }
    afr[kt] = a;
  }

  f32x4 cfr[8];
  #pragma unroll
  for(int ct = 0; ct < 8; ct++) cfr[ct] = (f32x4){0.f,0.f,0.f,0.f};
  #pragma unroll
  for(int kt = 0; kt < 2; kt++)
    #pragma unroll
    for(int ct = 0; ct < 8; ct++){
      bf16x8 bfr = *(const bf16x8*)&bwl[((kt*8 + ct)*64 + lane)*8];
      cfr[ct] = __builtin_amdgcn_mfma_f32_16x16x32_bf16(afr[kt], bfr, cfr[ct], 0, 0, 0);
    }

  #pragma unroll
  for(int i = 0; i < 4; i++){
    if(g*4 + i < bc){
      bf16x8 wpk;
      #pragma unroll
      for(int ct = 0; ct < 8; ct++) wpk[ct] = (short)f2bf(cfr[ct][i] * 0.125f);
      *(bf16x8*)(wper + (size_t)(p16 + g*4 + i)*128 + c0*8) = wpk;
    }
  }
}

// ---------------- phase 2: node-centric gather, software-pipelined batch loop ----------------
// Steady state: next batch's rec loads in flight during current batch's sv gather + math.
__global__ __launch_bounds__(256, 4) void k_msg(
    const unsigned short* __restrict__ sv, const unsigned short* __restrict__ wper,
    const unsigned short* __restrict__ edata, const int* __restrict__ offs,
    const float* __restrict__ W2s, const float* __restrict__ W2v,
    float* __restrict__ out, int N)
{
  __shared__ __align__(16) float nsl[4][256];          // [0..63]=ns, [64+c*64+m]=nv[c][m]
  __shared__ __align__(8) unsigned short w2sTb[32*68]; // w2sTb[o*68+m] = bf16(W2s[m][o])
  __shared__ __align__(8) unsigned short w2vTb[32*68]; // w2vTb[o*68+m] = bf16(W2v[m][o])
  const int t = threadIdx.x, lane = t & 63, wv = t >> 6;
  const int c0 = lane & 15, g = lane >> 4;

  {
    #pragma unroll
    for(int i = 0; i < 8; i++){
      int idx = t + i*256;          // 0..2047
      int m = idx >> 5, o = idx & 31;
      w2sTb[o*68 + m] = f2bf(W2s[idx]);
      w2vTb[o*68 + m] = f2bf(W2v[idx]);
    }
  }
  __syncthreads();

  const int n = blockIdx.x*4 + wv;
  if(n >= N) return;

  const float SC2 = 0.03125f;              // (1/sqrt64)*(1/sqrt16)
  const float IS3 = 0.57735026918962576f;  // 1/sqrt(3)

  float acc[16];
  #pragma unroll
  for(int i = 0; i < 16; i++) acc[i] = 0.f;

  const int eb0v = offs[n], eb1v = offs[n+1];
  if(eb0v < eb1v){
    int eb = eb0v;
    int bc = eb1v - eb; if(bc > 16) bc = 16;
    // prologue: load batch-0 records
    u32x4 rec0, rec1, rec2, rec3;
    {
      int e0i = eb + (( 0 + g) < bc ? ( 0 + g) : 0);
      int e1i = eb + (( 4 + g) < bc ? ( 4 + g) : 0);
      int e2i = eb + (( 8 + g) < bc ? ( 8 + g) : 0);
      int e3i = eb + ((12 + g) < bc ? (12 + g) : 0);
      rec0 = *(const u32x4*)(edata + (size_t)e0i*16 + 8);
      rec1 = *(const u32x4*)(edata + (size_t)e1i*16 + 8);
      rec2 = *(const u32x4*)(edata + (size_t)e2i*16 + 8);
      rec3 = *(const u32x4*)(edata + (size_t)e3i*16 + 8);
    }
    while(true){
      int ebn = eb + 16;
      int bcn = eb1v - ebn; if(bcn > 16) bcn = 16;
      bool has_next = ebn < eb1v;

      // phase A: prefetch next batch's records (hidden under this batch's gather+math)
      u32x4 recn0 = rec0, recn1 = rec1, recn2 = rec2, recn3 = rec3;
      if(has_next){
        int e0i = ebn + (( 0 + g) < bcn ? ( 0 + g) : 0);
        int e1i = ebn + (( 4 + g) < bcn ? ( 4 + g) : 0);
        int e2i = ebn + (( 8 + g) < bcn ? ( 8 + g) : 0);
        int e3i = ebn + ((12 + g) < bcn ? (12 + g) : 0);
        recn0 = *(const u32x4*)(edata + (size_t)e0i*16 + 8);
        recn1 = *(const u32x4*)(edata + (size_t)e1i*16 + 8);
        recn2 = *(const u32x4*)(edata + (size_t)e2i*16 + 8);
        recn3 = *(const u32x4*)(edata + (size_t)e3i*16 + 8);
      }

      // phase B: dependent sv gathers + independent wper loads for current batch
      bf16x8 sr0 = *(const bf16x8*)(sv + (size_t)(int)rec0.z*128 + c0*8);
      bf16x8 sr1 = *(const bf16x8*)(sv + (size_t)(int)rec1.z*128 + c0*8);
      bf16x8 sr2 = *(const bf16x8*)(sv + (size_t)(int)rec2.z*128 + c0*8);
      bf16x8 sr3 = *(const bf16x8*)(sv + (size_t)(int)rec3.z*128 + c0*8);
      bf16x8 w80, w81, w82, w83;
      {
        int e0i = eb + (( 0 + g) < bc ? ( 0 + g) : 0);
        int e1i = eb + (( 4 + g) < bc ? ( 4 + g) : 0);
        int e2i = eb + (( 8 + g) < bc ? ( 8 + g) : 0);
        int e3i = eb + ((12 + g) < bc ? (12 + g) : 0);
        w80 = *(const bf16x8*)(wper + (size_t)e0i*128 + c0*8);
        w81 = *(const bf16x8*)(wper + (size_t)e1i*128 + c0*8);
        w82 = *(const bf16x8*)(wper + (size_t)e2i*128 + c0*8);
        w83 = *(const bf16x8*)(wper + (size_t)e3i*128 + c0*8);
      }

      // phase C: predicated math
      #pragma unroll
      for(int r = 0; r < 4; r++){
        int es = r*4 + g;
        if(es >= bc) continue;
        u32x4  rec = (r == 0) ? rec0 : (r == 1) ? rec1 : (r == 2) ? rec2 : rec3;
        bf16x8 w8  = (r == 0) ? w80  : (r == 1) ? w81  : (r == 2) ? w82  : w83;
        bf16x8 sr  = (r == 0) ? sr0  : (r == 1) ? sr1  : (r == 2) ? sr2  : sr3;
        float e0  = bf2f((short)(rec.x & 0xffff));
        float e1x = bf2f((short)(rec.x >> 16));
        float e1y = bf2f((short)(rec.y & 0xffff));
        float e1z = bf2f((short)(rec.y >> 16));
        float w0A = bf2f(w8[0]), w0B = bf2f(w8[1]);
        float w1A = bf2f(w8[2]), w1B = bf2f(w8[3]);
        float w2A = bf2f(w8[4]), w2B = bf2f(w8[5]);
        float w3A = bf2f(w8[6]), w3B = bf2f(w8[7]);
        float ssA = bf2f(sr[0]), ssB = bf2f(sr[1]);
        float vA0 = bf2f(sr[2]), vB0 = bf2f(sr[3]);
        float vA1 = bf2f(sr[4]), vB1 = bf2f(sr[5]);
        float vA2 = bf2f(sr[6]), vB2 = bf2f(sr[7]);

        acc[0] += w0A*ssA*e0;
        acc[1] += w0B*ssB*e0;
        acc[2] += w3A*(vA0*e1x + vA1*e1y + vA2*e1z);
        acc[3] += w3B*(vB0*e1x + vB1*e1y + vB2*e1z);
        float h1A = w1A*ssA, h1B = w1B*ssB;
        acc[4]  += h1A*e1x; acc[5]  += h1A*e1y; acc[6]  += h1A*e1z;
        acc[7]  += h1B*e1x; acc[8]  += h1B*e1y; acc[9]  += h1B*e1z;
        float h2A = w2A*e0, h2B = w2B*e0;
        acc[10] += h2A*vA0; acc[11] += h2A*vA1; acc[12] += h2A*vA2;
        acc[13] += h2B*vB0; acc[14] += h2B*vB1; acc[15] += h2B*vB2;
      }

      if(!has_next) break;
      rec0 = recn0; rec1 = recn1; rec2 = recn2; rec3 = recn3;
      eb = ebn; bc = bcn;
    }
  }

  #pragma unroll
  for(int i = 0; i < 16; i++){
    acc[i] += __shfl_xor(acc[i], 16);
    acc[i] += __shfl_xor(acc[i], 32);
  }

  float* nl = nsl[wv];
  if(g == 0){
    nl[c0]      = acc[0];
    nl[16 + c0] = acc[1];
    nl[32 + c0] = acc[2]*IS3;
    nl[48 + c0] = acc[3]*IS3;
    #pragma unroll
    for(int cc = 0; cc < 3; cc++){
      nl[64 + cc*64 +  0 + c0] = acc[4  + cc];
      nl[64 + cc*64 + 16 + c0] = acc[7  + cc];
      nl[64 + cc*64 + 32 + c0] = acc[10 + cc];
      nl[64 + cc*64 + 48 + c0] = acc[13 + cc];
    }
  }
  __threadfence_block();

  const int t1 = lane, t2 = 64 + lane;
  int u1 = t1 - 32; if(u1 < 0) u1 = 0;
  const int w1i = u1/3, c1i = u1%3;
  const int w2i = (t2 - 32)/3, c2i = (t2 - 32)%3;
  const f32x4*  p1a = (const f32x4*)((t1 < 32) ? &nl[0] : &nl[64 + c1i*64]);
  const us16x4* p1b = (const us16x4*)((t1 < 32) ? &w2sTb[t1*68] : &w2vTb[w1i*68]);
  const f32x4*  p2a = (const f32x4*)&nl[64 + c2i*64];
  const us16x4* p2b = (const us16x4*)&w2vTb[w2i*68];
  float s1 = 0.f, s2 = 0.f;
  #pragma unroll
  for(int q = 0; q < 16; q++){
    f32x4 a = p1a[q];
    us16x4 b = p1b[q];
    f32x4 c = p2a[q];
    us16x4 d = p2b[q];
    s1 += a[0]*bf2f((short)b[0]) + a[1]*bf2f((short)b[1])
        + a[2]*bf2f((short)b[2]) + a[3]*bf2f((short)b[3]);
    s2 += c[0]*bf2f((short)d[0]) + c[1]*bf2f((short)d[1])
        + c[2]*bf2f((short)d[2]) + c[3]*bf2f((short)d[3]);
  }
  out[(size_t)n*128 + t1] += s1*SC2;
  out[(size_t)n*128 + t2] += s2*SC2;
}

extern "C" void kernel_launch(void* const* d_in, const int* in_sizes, int n_in,
                              void* d_out, int out_size, void* d_ws, size_t ws_size,
                              hipStream_t stream)
{
  const float* nf    = (const float*)d_in[0];
  const float* na    = (const float*)d_in[1];
  const float* eemb  = (const float*)d_in[2];
  const float* eattr = (const float*)d_in[3];
  const int*   eidx  = (const int*)d_in[4];
  const float* W1s   = (const float*)d_in[5];
  const float* W1v   = (const float*)d_in[6];
  const float* Wr0   = (const float*)d_in[7];
  const float* Wr1   = (const float*)d_in[8];
  const float* W2s   = (const float*)d_in[9];
  const float* W2v   = (const float*)d_in[10];
  const float* Wsc_s = (const float*)d_in[11];
  const float* Wsc_v = (const float*)d_in[12];
  float* out = (float*)d_out;

  int N = in_sizes[0]/128;
  int E = in_sizes[2]/8;
  int NB16 = (E + 15)/16;

  char* ws = (char*)d_ws;
  size_t off = 0;
  unsigned short* sv = (unsigned short*)(ws + off); off += (size_t)N*128*2;
  unsigned short* wper = (unsigned short*)(ws + off); off += (size_t)NB16*16*128*2;
  unsigned short* edata = (unsigned short*)(ws + off); off += (size_t)NB16*16*32;  // 32B records
  int* cnt    = (int*)(ws + off);             off += (size_t)N*4;
  int* offs   = (int*)(ws + off);             off += (size_t)(N+1)*4;
  int* cursor = (int*)(ws + off);             off += (size_t)N*4;
  int* bsum   = (int*)(ws + off);             off += 4096;
  unsigned short* wr1frag = (unsigned short*)(ws + off); off += 16384;
  float* wr0p = (float*)(ws + off);           off += 2048;
  unsigned short* wscfrag = (unsigned short*)(ws + off); off += 65536;
  unsigned short* w1frag = (unsigned short*)(ws + off);  off += 4096;

  int NB = (N + 1023)/1024;

  (void)hipMemsetAsync(cnt, 0, (size_t)N*4, stream);
  k_count_prep<<<dim3((E+255)/256), dim3(256), 0, stream>>>(eidx, E, cnt, Wr0, Wr1,
                                                            Wsc_s, Wsc_v, W1s, W1v,
                                                            wr1frag, wr0p, wscfrag, w1frag);
  k_scan_a <<<dim3(NB),          dim3(1024),0, stream>>>(cnt, N, offs, bsum);
  k_scan_b <<<dim3(1),           dim3(64),  0, stream>>>(bsum, NB, offs, N);
  k_scan_c <<<dim3(NB),          dim3(1024),0, stream>>>(offs, bsum, cursor, N);
  k_perm   <<<dim3((E+255)/256), dim3(256), 0, stream>>>(eemb, eattr, eidx, E, cursor, edata);
  k_node   <<<dim3((N+63)/64),   dim3(256), 0, stream>>>(nf, na, w1frag, wscfrag, sv, out, N);
  k_wedge  <<<dim3((NB16+3)/4),  dim3(256), 0, stream>>>(edata, wr1frag, wr0p, wper, NB16, E);
  k_msg    <<<dim3((N+3)/4),     dim3(256), 0, stream>>>(sv, wper, edata, offs,
                                                         W2s, W2v, out, N);
}